// Round 2
// baseline (452.008 us; speedup 1.0000x reference)
//
#include <hip/hip_runtime.h>
#include <hip/hip_bf16.h>
#include <stdint.h>

typedef short v8s __attribute__((ext_vector_type(8)));
typedef float v4f __attribute__((ext_vector_type(4)));
typedef float v4fv __attribute__((ext_vector_type(4)));

__device__ __forceinline__ float bf2f(short s) {
    unsigned int u = ((unsigned int)(unsigned short)s) << 16;
    float f;
    __builtin_memcpy(&f, &u, 4);
    return f;
}

__device__ __forceinline__ unsigned short f2bf(float f) {
    unsigned int u;
    __builtin_memcpy(&u, &f, 4);
    unsigned int r = (u + 0x7FFFu + ((u >> 16) & 1u)) >> 16;  // RNE
    return (unsigned short)r;
}

__device__ __forceinline__ float tanh_fast(float z) {
    // tanh(z) = 1 - 2/(exp(2z)+1); exp saturation gives exact +-1 limits
    float e = __expf(2.0f * z);
    return 1.0f - 2.0f / (e + 1.0f);
}

// ---------------------------------------------------------------------------
// Phase A: ux[t][b][i] = sum_e x[b][t][e]*Uw[i][e] + Ub[i] + Wb[i]   (f32)
// ---------------------------------------------------------------------------
__global__ __launch_bounds__(256) void ux_kernel(
    const float* __restrict__ x, const float* __restrict__ Uw,
    const float* __restrict__ Ub, const float* __restrict__ Wb,
    float* __restrict__ ux) {
    int row = blockIdx.x * 2 + (threadIdx.x >> 7);  // row = t*32 + b
    int i = threadIdx.x & 127;
    int b = row & 31, t = row >> 5;
    const float* xr = x + (b * 200 + t) * 32;
    const float* ur = Uw + i * 32;
    float acc = 0.f;
#pragma unroll
    for (int e4 = 0; e4 < 8; ++e4) {
        v4fv xv = *(const v4fv*)(xr + e4 * 4);
        v4fv uv = *(const v4fv*)(ur + e4 * 4);
#pragma unroll
        for (int j = 0; j < 4; ++j) acc = __builtin_fmaf(xv[j], uv[j], acc);
    }
    ux[row * 128 + i] = acc + Ub[i] + Wb[i];
}

// ---------------------------------------------------------------------------
// Phase B: recurrence via split-bf16 MFMA (hi+lo ~= f32 precision).
// 2 workgroups (batches 0-15 / 16-31), 512 threads = 8 waves; wave w owns
// hidden cols [16w,16w+16). h hi/lo in double-buffered LDS (stride 136:
// 272B rows -> 2-way bank alias = free). Ww hi/lo fragments in registers.
// ---------------------------------------------------------------------------
__global__ __launch_bounds__(512) void rnn_kernel(
    const float* __restrict__ Ww, const float* __restrict__ ux,
    short* __restrict__ hs, float* __restrict__ hidden_out) {
    __shared__ alignas(16) short h_hi[2][16][136];
    __shared__ alignas(16) short h_lo[2][16][136];
    const int tid = threadIdx.x;
    const int w = tid >> 6;
    const int lane = tid & 63;
    const int q = lane >> 4, c = lane & 15;
    const int b0 = blockIdx.x * 16;
    const int col = 16 * w + c;

    for (int i = tid; i < 2 * 16 * 136; i += 512) {
        ((short*)h_hi)[i] = 0;
        ((short*)h_lo)[i] = 0;
    }

    // B-fragments: B[k][n] = Ww[n][k]; lane holds n=col, k=32kb+8q+j. Split hi/lo.
    v8s w_hi[4], w_lo[4];
#pragma unroll
    for (int kb = 0; kb < 4; ++kb) {
        const float* p = Ww + col * 128 + 32 * kb + 8 * q;
#pragma unroll
        for (int j = 0; j < 8; ++j) {
            float v = p[j];
            unsigned short hi = f2bf(v);
            w_hi[kb][j] = (short)hi;
            w_lo[kb][j] = (short)f2bf(v - bf2f((short)hi));
        }
    }

    float uxv[4];
#pragma unroll
    for (int r = 0; r < 4; ++r)
        uxv[r] = ux[(b0 + 4 * q + r) * 128 + col];  // t = 0

    __syncthreads();

    for (int t = 0; t < 200; ++t) {
        float uxn[4];
        int tn = t < 199 ? t + 1 : 199;
#pragma unroll
        for (int r = 0; r < 4; ++r)
            uxn[r] = ux[(tn * 32 + b0 + 4 * q + r) * 128 + col];

        const int rb = t & 1;
        v4f a0 = {0.f, 0.f, 0.f, 0.f}, a1 = a0, a2 = a0;
#pragma unroll
        for (int kb = 0; kb < 4; ++kb) {
            v8s ahi = *(const v8s*)(&h_hi[rb][c][32 * kb + 8 * q]);
            v8s alo = *(const v8s*)(&h_lo[rb][c][32 * kb + 8 * q]);
            a0 = __builtin_amdgcn_mfma_f32_16x16x32_bf16(ahi, w_hi[kb], a0, 0, 0, 0);
            a1 = __builtin_amdgcn_mfma_f32_16x16x32_bf16(ahi, w_lo[kb], a1, 0, 0, 0);
            a2 = __builtin_amdgcn_mfma_f32_16x16x32_bf16(alo, w_hi[kb], a2, 0, 0, 0);
        }

#pragma unroll
        for (int r = 0; r < 4; ++r) {
            float z = ((a0[r] + a1[r]) + a2[r]) + uxv[r];
            float h = tanh_fast(z);
            unsigned short hh = f2bf(h);
            float rem = h - bf2f((short)hh);
            unsigned short hl = f2bf(rem);
            h_hi[rb ^ 1][4 * q + r][col] = (short)hh;
            h_lo[rb ^ 1][4 * q + r][col] = (short)hl;
            hs[((b0 + 4 * q + r) * 200 + t) * 128 + col] = (short)hh;
            if (t == 199) hidden_out[(b0 + 4 * q + r) * 128 + col] = h;
            uxv[r] = uxn[r];
        }
        __syncthreads();
    }
}

// ---------------------------------------------------------------------------
// Phase C: out[bt][v] = sum_k hs[bt][k]*Vw[v][k] + Vb[v]   (f32 out)
// Swapped-operand MFMA (A=Vw, B=hs): lane's 4 acc regs = 4 consecutive v
// -> one float4 store per subtile. bf16 rounding of Vw/hs (err ~0.0015).
// ---------------------------------------------------------------------------
__global__ __launch_bounds__(256) void out_kernel(
    const short* __restrict__ hs, const float* __restrict__ Vw,
    const float* __restrict__ Vb, float* __restrict__ out) {
    const int tid = threadIdx.x;
    const int w = tid >> 6;
    const int lane = tid & 63;
    const int q = lane >> 4, c = lane & 15;
    const int v_wave = blockIdx.x * 128 + 32 * w;
    const int bt0 = blockIdx.y * 128;

    v4f acc[2][8];
#pragma unroll
    for (int a = 0; a < 2; ++a)
#pragma unroll
        for (int b = 0; b < 8; ++b) acc[a][b] = (v4f){0.f, 0.f, 0.f, 0.f};

#pragma unroll
    for (int kb = 0; kb < 4; ++kb) {
        v8s afr[2];
#pragma unroll
        for (int vt = 0; vt < 2; ++vt) {
            int vr = v_wave + 16 * vt + c;
            vr = vr < 8000 ? vr : 7999;  // clamp OOB rows (last tile)
            const float* p = Vw + vr * 128 + 32 * kb + 8 * q;
            v4fv p0 = *(const v4fv*)(p);
            v4fv p1 = *(const v4fv*)(p + 4);
#pragma unroll
            for (int j = 0; j < 4; ++j) {
                afr[vt][j] = (short)f2bf(p0[j]);
                afr[vt][4 + j] = (short)f2bf(p1[j]);
            }
        }
#pragma unroll
        for (int nt = 0; nt < 8; ++nt) {
            v8s bfr = *(const v8s*)(hs + (bt0 + 16 * nt + c) * 128 + 32 * kb + 8 * q);
            acc[0][nt] = __builtin_amdgcn_mfma_f32_16x16x32_bf16(afr[0], bfr, acc[0][nt], 0, 0, 0);
            acc[1][nt] = __builtin_amdgcn_mfma_f32_16x16x32_bf16(afr[1], bfr, acc[1][nt], 0, 0, 0);
        }
    }

#pragma unroll
    for (int vt = 0; vt < 2; ++vt) {
        int v4base = v_wave + 16 * vt + 4 * q;  // lane's 4 consecutive v
        bool ok = v4base < 8000;                // multiple of 4; 8000 % 4 == 0
        int vb_idx = ok ? v4base : 0;
        v4fv vbv = *(const v4fv*)(Vb + vb_idx);
#pragma unroll
        for (int nt = 0; nt < 8; ++nt) {
            long bt = bt0 + 16 * nt + c;
            if (ok) {
                v4fv o;
#pragma unroll
                for (int r = 0; r < 4; ++r) o[r] = acc[vt][nt][r] + vbv[r];
                *(v4fv*)(out + bt * 8000 + v4base) = o;
            }
        }
    }
}

extern "C" void kernel_launch(void* const* d_in, const int* in_sizes, int n_in,
                              void* d_out, int out_size, void* d_ws, size_t ws_size,
                              hipStream_t stream) {
    const float* x  = (const float*)d_in[0];  // [32][200][32]
    const float* Ww = (const float*)d_in[1];  // [128][128]
    const float* Wb = (const float*)d_in[2];  // [128]
    const float* Uw = (const float*)d_in[3];  // [128][32]
    const float* Ub = (const float*)d_in[4];  // [128]
    const float* Vw = (const float*)d_in[5];  // [8000][128]
    const float* Vb = (const float*)d_in[6];  // [8000]
    float* out = (float*)d_out;               // [32][200][8000] ++ [32][128]

    float* ux = (float*)d_ws;                         // 819200 f32 = 3.28 MB
    short* hs = (short*)((char*)d_ws + 819200 * 4);   // 819200 bf16 = 1.64 MB

    ux_kernel<<<3200, 256, 0, stream>>>(x, Uw, Ub, Wb, ux);
    rnn_kernel<<<2, 512, 0, stream>>>(Ww, ux, hs, out + 51200000);
    dim3 g(63, 50);
    out_kernel<<<g, 256, 0, stream>>>(hs, Vw, Vb, out);
}

// Round 3
// 404.973 us; speedup vs baseline: 1.1161x; 1.1161x over previous
//
#include <hip/hip_runtime.h>
#include <stdint.h>

typedef short v8s __attribute__((ext_vector_type(8)));
typedef float v4f __attribute__((ext_vector_type(4)));

__device__ __forceinline__ float bf2f(short s) {
    unsigned int u = ((unsigned int)(unsigned short)s) << 16;
    float f; __builtin_memcpy(&f, &u, 4); return f;
}
__device__ __forceinline__ unsigned short f2bf_rne(float f) {
    unsigned int u; __builtin_memcpy(&u, &f, 4);
    return (unsigned short)((u + 0x7FFFu + ((u >> 16) & 1u)) >> 16);
}
__device__ __forceinline__ unsigned short f2bf_rhu(float f) {  // round-half-up (2 ops)
    unsigned int u; __builtin_memcpy(&u, &f, 4);
    return (unsigned short)((u + 0x8000u) >> 16);
}
__device__ __forceinline__ unsigned short f2bf_trunc(float f) {  // 1 op
    unsigned int u; __builtin_memcpy(&u, &f, 4);
    return (unsigned short)(u >> 16);
}
__device__ __forceinline__ float tanh_fast(float z) {
    float e = __expf(2.0f * z);                      // v_mul + v_exp
    float r = __builtin_amdgcn_rcpf(e + 1.0f);       // v_add + v_rcp (no slow divide)
    return __builtin_fmaf(-2.0f, r, 1.0f);           // exact +-1 at saturation
}

// ---------------------------------------------------------------------------
// Phase A: ux[t][b][i] = sum_e x[b][t][e]*Uw[i][e] + Ub[i] + Wb[i]   (f32)
// ---------------------------------------------------------------------------
__global__ __launch_bounds__(256) void ux_kernel(
    const float* __restrict__ x, const float* __restrict__ Uw,
    const float* __restrict__ Ub, const float* __restrict__ Wb,
    float* __restrict__ ux) {
    int row = blockIdx.x * 2 + (threadIdx.x >> 7);  // row = t*32 + b
    int i = threadIdx.x & 127;
    int b = row & 31, t = row >> 5;
    const float* xr = x + (b * 200 + t) * 32;
    const float* ur = Uw + i * 32;
    float acc = 0.f;
#pragma unroll
    for (int e4 = 0; e4 < 8; ++e4) {
        v4f xv = *(const v4f*)(xr + e4 * 4);
        v4f uv = *(const v4f*)(ur + e4 * 4);
#pragma unroll
        for (int j = 0; j < 4; ++j) acc = __builtin_fmaf(xv[j], uv[j], acc);
    }
    ux[row * 128 + i] = acc + Ub[i] + Wb[i];
}

// ---------------------------------------------------------------------------
// Vw f32 -> bf16 (RNE), once.  8 elements/thread.
// ---------------------------------------------------------------------------
__global__ __launch_bounds__(256) void vwcvt_kernel(
    const float* __restrict__ Vw, short* __restrict__ vwb) {
    int i = (blockIdx.x * 256 + threadIdx.x) * 8;
    v4f p0 = *(const v4f*)(Vw + i);
    v4f p1 = *(const v4f*)(Vw + i + 4);
    v8s o;
#pragma unroll
    for (int j = 0; j < 4; ++j) {
        o[j] = (short)f2bf_rne(p0[j]);
        o[4 + j] = (short)f2bf_rne(p1[j]);
    }
    *(v8s*)(vwb + i) = o;
}

// ---------------------------------------------------------------------------
// Phase B: recurrence, split-bf16 (hi+lo) MFMA.  2 WGs x 512 thr (8 waves).
// h hi/lo double-buffered in one LDS array; unroll-by-2 makes every LDS
// offset an immediate.  ux folded into MFMA C-init.  All global pointers
// incremented (no per-step address recompute).
// hs layout: [t][32][128] bf16 (out_kernel maps indices accordingly).
// ---------------------------------------------------------------------------
__global__ __launch_bounds__(512) void rnn_kernel(
    const float* __restrict__ Ww, const float* __restrict__ ux,
    short* __restrict__ hs, float* __restrict__ hidden_out) {
    // [buf][hi=0/lo=1][row 16][col 136]; strides: buf 8704B, plane 4352B, row 272B
    __shared__ alignas(16) short hbuf[2 * 2 * 16 * 136];
    char* lds = (char*)hbuf;
    const int tid = threadIdx.x;
    const int w = tid >> 6, lane = tid & 63, q = lane >> 4, c = lane & 15;
    const int b0 = blockIdx.x * 16;
    const int col = 16 * w + c;

    // zero both buffers (h0 = 0), 16B stores
    for (int i = tid; i < 1088; i += 512) ((v8s*)hbuf)[i] = (v8s){0, 0, 0, 0, 0, 0, 0, 0};

    // Ww B-fragments, split hi/lo: B[k][n]=Ww[n][k]; lane: n=col, k=32kb+8q+j
    v8s w_hi[4], w_lo[4];
#pragma unroll
    for (int kb = 0; kb < 4; ++kb) {
        const float* p = Ww + col * 128 + 32 * kb + 8 * q;
#pragma unroll
        for (int j = 0; j < 8; ++j) {
            float v = p[j];
            unsigned short hi = f2bf_rne(v);
            w_hi[kb][j] = (short)hi;
            w_lo[kb][j] = (short)f2bf_rne(v - bf2f((short)hi));
        }
    }

    const int rd_base = c * 272 + 16 * q;      // A-frag: row c, k-offset 8q (bytes)
    const int wr_base = q * 1088 + col * 2;    // C rows 4q+r, col (bytes)

    // t=0 ux; then uxp points at t+1 for prefetch (imm offsets r*512B)
    const float* uxp = ux + (b0 + 4 * q) * 128 + col;
    float uxv0 = uxp[0], uxv1 = uxp[128], uxv2 = uxp[256], uxv3 = uxp[384];
    uxp += 4096;
    short* hsp = hs + (b0 + 4 * q) * 128 + col;  // [t][b][h], t-stride 4096

    __syncthreads();

#define RNN_STEP(RBUF, WBUF)                                                        \
    {                                                                               \
        float un0 = uxp[0], un1 = uxp[128], un2 = uxp[256], un3 = uxp[384];         \
        v4f a0 = {uxv0, uxv1, uxv2, uxv3};                                          \
        v4f a1 = {0.f, 0.f, 0.f, 0.f}, a2 = a1;                                     \
        _Pragma("unroll") for (int kb = 0; kb < 4; ++kb) {                          \
            v8s ahi = *(const v8s*)(lds + (RBUF)*8704 + kb * 64 + rd_base);         \
            v8s alo = *(const v8s*)(lds + (RBUF)*8704 + 4352 + kb * 64 + rd_base);  \
            a0 = __builtin_amdgcn_mfma_f32_16x16x32_bf16(ahi, w_hi[kb], a0, 0, 0, 0); \
            a1 = __builtin_amdgcn_mfma_f32_16x16x32_bf16(ahi, w_lo[kb], a1, 0, 0, 0); \
            a2 = __builtin_amdgcn_mfma_f32_16x16x32_bf16(alo, w_hi[kb], a2, 0, 0, 0); \
        }                                                                           \
        _Pragma("unroll") for (int r = 0; r < 4; ++r) {                             \
            float z = (a0[r] + a1[r]) + a2[r];                                      \
            float h = tanh_fast(z);                                                 \
            unsigned short hh = f2bf_rhu(h);                                        \
            float rem = h - bf2f((short)hh);                                        \
            unsigned short hl = f2bf_trunc(rem);                                    \
            *(short*)(lds + (WBUF)*8704 + r * 272 + wr_base) = (short)hh;           \
            *(short*)(lds + (WBUF)*8704 + 4352 + r * 272 + wr_base) = (short)hl;    \
            hsp[r * 128] = (short)hh;                                               \
        }                                                                           \
        uxv0 = un0; uxv1 = un1; uxv2 = un2; uxv3 = un3;                             \
        uxp += 4096; hsp += 4096;                                                   \
        __syncthreads();                                                            \
    }

    for (int tp = 0; tp < 100; ++tp) {
        RNN_STEP(0, 1)  // even t: read buf0, write buf1
        RNN_STEP(1, 0)  // odd  t: read buf1, write buf0
        // note: at t=199 the prefetch reads 16KB past ux (into hs region of
        // d_ws) — in-bounds of ws, values never used, cannot be NaN-typed UB.
    }
#undef RNN_STEP

    // final h (t=199 wrote buf0); each lane reads its own writes — no barrier
#pragma unroll
    for (int r = 0; r < 4; ++r) {
        short hh = *(short*)(lds + r * 272 + wr_base);
        short hl = *(short*)(lds + 4352 + r * 272 + wr_base);
        hidden_out[(b0 + 4 * q + r) * 128 + col] = bf2f(hh) + bf2f(hl);
    }
}

// ---------------------------------------------------------------------------
// Phase C: out[b][t][v] = sum_k hs[tb][k]*Vw[v][k] + Vb[v]   (f32 out)
// A=Vw(bf16 pre-converted), B=hs: lane's 4 acc regs = 4 consecutive v
// -> one float4 store.  hs rows are tb = t*32+b; output addr remapped.
// ---------------------------------------------------------------------------
__global__ __launch_bounds__(256) void out_kernel(
    const short* __restrict__ hs, const short* __restrict__ vwb,
    const float* __restrict__ Vb, float* __restrict__ out) {
    const int tid = threadIdx.x;
    const int w = tid >> 6, lane = tid & 63, q = lane >> 4, c = lane & 15;
    const int v_wave = blockIdx.x * 128 + 32 * w;
    const int n0 = blockIdx.y * 128;  // tb-tile base

    v4f acc[2][8];
#pragma unroll
    for (int a = 0; a < 2; ++a)
#pragma unroll
        for (int b = 0; b < 8; ++b) acc[a][b] = (v4f){0.f, 0.f, 0.f, 0.f};

#pragma unroll
    for (int kb = 0; kb < 4; ++kb) {
        v8s afr[2];
#pragma unroll
        for (int vt = 0; vt < 2; ++vt) {
            int vr = v_wave + 16 * vt + c;
            vr = vr < 8000 ? vr : 7999;  // OOB rows: garbage acc, store-masked
            afr[vt] = *(const v8s*)(vwb + vr * 128 + 32 * kb + 8 * q);
        }
#pragma unroll
        for (int nt = 0; nt < 8; ++nt) {
            v8s bfr = *(const v8s*)(hs + (n0 + 16 * nt + c) * 128 + 32 * kb + 8 * q);
            acc[0][nt] = __builtin_amdgcn_mfma_f32_16x16x32_bf16(afr[0], bfr, acc[0][nt], 0, 0, 0);
            acc[1][nt] = __builtin_amdgcn_mfma_f32_16x16x32_bf16(afr[1], bfr, acc[1][nt], 0, 0, 0);
        }
    }

#pragma unroll
    for (int vt = 0; vt < 2; ++vt) {
        int v4base = v_wave + 16 * vt + 4 * q;  // lane's 4 consecutive v
        bool ok = v4base < 8000;                // tile-aligned, 8000 % 4 == 0
        v4f vbv = *(const v4f*)(Vb + (ok ? v4base : 0));
#pragma unroll
        for (int nt = 0; nt < 8; ++nt) {
            int n = n0 + 16 * nt + c;           // tb index
            int t = n >> 5, b = n & 31;
            unsigned int off = (unsigned int)(b * 200 + t) * 8000u + (unsigned int)v4base;
            if (ok) {
                v4f o;
#pragma unroll
                for (int r = 0; r < 4; ++r) o[r] = acc[vt][nt][r] + vbv[r];
                *(v4f*)(out + (size_t)off) = o;
            }
        }
    }
}

extern "C" void kernel_launch(void* const* d_in, const int* in_sizes, int n_in,
                              void* d_out, int out_size, void* d_ws, size_t ws_size,
                              hipStream_t stream) {
    const float* x  = (const float*)d_in[0];  // [32][200][32]
    const float* Ww = (const float*)d_in[1];  // [128][128]
    const float* Wb = (const float*)d_in[2];  // [128]
    const float* Uw = (const float*)d_in[3];  // [128][32]
    const float* Ub = (const float*)d_in[4];  // [128]
    const float* Vw = (const float*)d_in[5];  // [8000][128]
    const float* Vb = (const float*)d_in[6];  // [8000]
    float* out = (float*)d_out;               // [32][200][8000] ++ [32][128]

    float* ux = (float*)d_ws;                         // 819200 f32 = 3.277 MB
    short* hs = (short*)((char*)d_ws + 3276800);      // 819200 bf16 = 1.638 MB
    short* vwb = (short*)d_ws;                        // aliases ux (dead after rnn)

    ux_kernel<<<3200, 256, 0, stream>>>(x, Uw, Ub, Wb, ux);
    rnn_kernel<<<2, 512, 0, stream>>>(Ww, ux, hs, out + 51200000);
    vwcvt_kernel<<<500, 256, 0, stream>>>(Vw, vwb);   // after rnn: ux is dead
    dim3 g(63, 50);
    out_kernel<<<g, 256, 0, stream>>>(hs, vwb, Vb, out);
}